// Round 5
// baseline (2400.966 us; speedup 1.0000x reference)
//
#include <hip/hip_runtime.h>
#include <math.h>

#define EPS 1e-5f

__device__ __forceinline__ float wave_sum64(float v) {
#pragma unroll
  for (int off = 32; off >= 1; off >>= 1) v += __shfl_xor(v, off, 64);
  return v;
}

// K1: x = weather @ W_emb + b_emb + pos_encoding
__global__ __launch_bounds__(64) void k_embed(
    const float* __restrict__ weather, const float* __restrict__ coords,
    const float* __restrict__ W_emb, const float* __restrict__ b_emb,
    float* __restrict__ x) {
  int row = blockIdx.x;  // b*1024 + s
  int e = threadIdx.x;
  int b = row >> 10, s = row & 1023;
  __shared__ float wrow[32];
  if (e < 31) wrow[e] = weather[row * 31 + e];
  __syncthreads();
  float acc = b_emb[e];
#pragma unroll
  for (int i = 0; i < 31; ++i) acc = fmaf(wrow[i], W_emb[i * 64 + e], acc);
  int g = e >> 2, rem = e & 3;
  float div = __expf(-0.5756462732485115f * (float)g);
  float pe;
  if (rem == 0)      pe = sinf((float)s * div);
  else if (rem == 1) pe = cosf((float)s * div);
  else if (rem == 2) pe = sinf(coords[b * 2 + 0] * 0.017453292519943295f * div);
  else               pe = cosf(coords[b * 2 + 1] * 0.017453292519943295f * div);
  x[row * 64 + e] = acc + pe;
}

// K2: qkv projection, written straight into attention-friendly layouts:
//   q2[bh][s2][8]   (gran added)
//   kv2[bh][key][16] = K(8) || V(8)  (gran added to K)
// bh = 8*(s%8)+h ; s2 = b*128 + s/8 ; hd = e%8.  8 rows/block, thread = col.
__global__ __launch_bounds__(192) void k_qkv(
    const float* __restrict__ x, const float* __restrict__ Wq,
    const float* __restrict__ bq, const float* __restrict__ gran,
    const int* __restrict__ tidx, float* __restrict__ q2,
    float* __restrict__ kv2) {
  int t = threadIdx.x;
  int row0 = blockIdx.x << 3;
  float acc[8];
  float bias = bq[t];
#pragma unroll
  for (int r = 0; r < 8; ++r) acc[r] = bias;
  const float* xp = x + (size_t)row0 * 64;
#pragma unroll 4
  for (int k4 = 0; k4 < 16; ++k4) {
    float4 xv[8];
#pragma unroll
    for (int r = 0; r < 8; ++r) xv[r] = *(const float4*)(xp + r * 64 + k4 * 4);
    float w0 = Wq[(4 * k4 + 0) * 192 + t];
    float w1 = Wq[(4 * k4 + 1) * 192 + t];
    float w2 = Wq[(4 * k4 + 2) * 192 + t];
    float w3 = Wq[(4 * k4 + 3) * 192 + t];
#pragma unroll
    for (int r = 0; r < 8; ++r) {
      acc[r] = fmaf(xv[r].x, w0, acc[r]);
      acc[r] = fmaf(xv[r].y, w1, acc[r]);
      acc[r] = fmaf(xv[r].z, w2, acc[r]);
      acc[r] = fmaf(xv[r].w, w3, acc[r]);
    }
  }
  int cq = t & 63;
  int hh = cq >> 3, hd = t & 7;
  bool isqk = t < 128;
  int b = row0 >> 10, shi = (row0 & 1023) >> 3;
  int s2 = (b << 7) | shi;  // same for all 8 rows (row0 % 8 == 0)
#pragma unroll
  for (int r = 0; r < 8; ++r) {
    float o = acc[r];
    if (isqk) o += gran[tidx[2 * r + 1] * 64 + cq];  // (row0+r)%8 == r
    int bh = (r << 3) | hh;
    size_t base = ((size_t)(bh << 10) | s2);
    if (t < 64)       q2[(base << 3) + hd] = o;
    else if (t < 128) kv2[(base << 4) + hd] = o;
    else              kv2[(base << 4) + 8 + hd] = o;
  }
}

// K3: flash attention. Block = (bh, 64-query chunk), 256 threads =
// 64 queries x 4 key-splits (lane = 4*ql + ks, split-merge via shfl).
// K/V streamed through a 16KB double-buffered LDS tile (128 keys/tile).
// Register-budget bracket (learned rounds 3+4): natural liveness ~100 VGPR.
//   (256,4) -> 64-VGPR cap -> spill catastrophe (5.3 GB scratch traffic).
//   unbounded -> compiler may schedule to 256 VGPR -> 1 wave/SIMD + spills.
//   (256,2) -> 128-VGPR cap: above liveness, below blowup. Keep it.
__global__ __launch_bounds__(256, 2) void k_attn(
    const float* __restrict__ q2, const float* __restrict__ kv2,
    float* __restrict__ ao) {
  int bh = blockIdx.x >> 4, chunk = blockIdx.x & 15;
  int slo = bh >> 3, h = bh & 7;
  int t = threadIdx.x;
  int ql = t >> 2, ks = t & 3;
  int j = (chunk << 6) | ql;  // query s2

  const float* qb = q2 + ((((size_t)bh << 10) | j) << 3);
  float4 q0 = *(const float4*)qb;
  float4 q1 = *(const float4*)(qb + 4);
  const float scl = 0.35355339059327373f;  // 8^-0.5
  q0.x *= scl; q0.y *= scl; q0.z *= scl; q0.w *= scl;
  q1.x *= scl; q1.y *= scl; q1.z *= scl; q1.w *= scl;

  __shared__ float tile[2][2048];  // [buf][128 keys x 16 floats]
  const float* kvb = kv2 + ((size_t)bh << 14);

  // prologue: stage tile 0
  float4 p0 = *(const float4*)(kvb + (t << 2));
  float4 p1 = *(const float4*)(kvb + ((t + 256) << 2));
  ((float4*)tile[0])[t] = p0;
  ((float4*)tile[0])[t + 256] = p1;

  float m = -1e30f, lsum = 0.f;
  float a[8];
#pragma unroll
  for (int i = 0; i < 8; ++i) a[i] = 0.f;

  for (int tt = 0; tt < 8; ++tt) {
    if (tt < 7) {  // prefetch next tile into regs (in flight across barrier)
      const float* srcn = kvb + ((size_t)(tt + 1) << 11);
      p0 = *(const float4*)(srcn + (t << 2));
      p1 = *(const float4*)(srcn + ((t + 256) << 2));
    }
    __syncthreads();  // tile[tt&1] ready; prev compute done everywhere
    const float4* tb = (const float4*)tile[tt & 1];
#pragma unroll
    for (int g = 0; g < 8; ++g) {
      int i0 = (g << 4) | ks;  // keys i0, i0+4, i0+8, i0+12
      const float4* r0 = tb + ((i0 + 0) << 2);
      const float4* r1 = tb + ((i0 + 4) << 2);
      const float4* r2 = tb + ((i0 + 8) << 2);
      const float4* r3 = tb + ((i0 + 12) << 2);
      float4 ka0 = r0[0], kb0 = r0[1];
      float4 ka1 = r1[0], kb1 = r1[1];
      float4 ka2 = r2[0], kb2 = r2[1];
      float4 ka3 = r3[0], kb3 = r3[1];
      float s0 = q0.x*ka0.x + q0.y*ka0.y + q0.z*ka0.z + q0.w*ka0.w
               + q1.x*kb0.x + q1.y*kb0.y + q1.z*kb0.z + q1.w*kb0.w;
      float s1 = q0.x*ka1.x + q0.y*ka1.y + q0.z*ka1.z + q0.w*ka1.w
               + q1.x*kb1.x + q1.y*kb1.y + q1.z*kb1.z + q1.w*kb1.w;
      float s2 = q0.x*ka2.x + q0.y*ka2.y + q0.z*ka2.z + q0.w*ka2.w
               + q1.x*kb2.x + q1.y*kb2.y + q1.z*kb2.z + q1.w*kb2.w;
      float s3 = q0.x*ka3.x + q0.y*ka3.y + q0.z*ka3.z + q0.w*ka3.w
               + q1.x*kb3.x + q1.y*kb3.y + q1.z*kb3.z + q1.w*kb3.w;
      float mx = fmaxf(fmaxf(s0, s1), fmaxf(s2, s3));
      float nm = fmaxf(m, mx);
      float esc = __expf(m - nm);
      float e0 = __expf(s0 - nm), e1 = __expf(s1 - nm);
      float e2 = __expf(s2 - nm), e3 = __expf(s3 - nm);
      lsum = lsum * esc + (e0 + e1) + (e2 + e3);
      m = nm;
      // per-row V accumulation (identical rounding to the former nested
      // fma chain, but only one V row = 8 floats live at a time)
#pragma unroll
      for (int i = 0; i < 8; ++i) a[i] *= esc;
      {
        float4 va = r0[2], vb = r0[3];
        a[0] = fmaf(e0, va.x, a[0]); a[1] = fmaf(e0, va.y, a[1]);
        a[2] = fmaf(e0, va.z, a[2]); a[3] = fmaf(e0, va.w, a[3]);
        a[4] = fmaf(e0, vb.x, a[4]); a[5] = fmaf(e0, vb.y, a[5]);
        a[6] = fmaf(e0, vb.z, a[6]); a[7] = fmaf(e0, vb.w, a[7]);
      }
      {
        float4 va = r1[2], vb = r1[3];
        a[0] = fmaf(e1, va.x, a[0]); a[1] = fmaf(e1, va.y, a[1]);
        a[2] = fmaf(e1, va.z, a[2]); a[3] = fmaf(e1, va.w, a[3]);
        a[4] = fmaf(e1, vb.x, a[4]); a[5] = fmaf(e1, vb.y, a[5]);
        a[6] = fmaf(e1, vb.z, a[6]); a[7] = fmaf(e1, vb.w, a[7]);
      }
      {
        float4 va = r2[2], vb = r2[3];
        a[0] = fmaf(e2, va.x, a[0]); a[1] = fmaf(e2, va.y, a[1]);
        a[2] = fmaf(e2, va.z, a[2]); a[3] = fmaf(e2, va.w, a[3]);
        a[4] = fmaf(e2, vb.x, a[4]); a[5] = fmaf(e2, vb.y, a[5]);
        a[6] = fmaf(e2, vb.z, a[6]); a[7] = fmaf(e2, vb.w, a[7]);
      }
      {
        float4 va = r3[2], vb = r3[3];
        a[0] = fmaf(e3, va.x, a[0]); a[1] = fmaf(e3, va.y, a[1]);
        a[2] = fmaf(e3, va.z, a[2]); a[3] = fmaf(e3, va.w, a[3]);
        a[4] = fmaf(e3, vb.x, a[4]); a[5] = fmaf(e3, vb.y, a[5]);
        a[6] = fmaf(e3, vb.z, a[6]); a[7] = fmaf(e3, vb.w, a[7]);
      }
    }
    if (tt < 7) {  // safe: everyone passed this iter's barrier
      ((float4*)tile[(tt + 1) & 1])[t] = p0;
      ((float4*)tile[(tt + 1) & 1])[t + 256] = p1;
    }
  }

  // merge the 4 key-splits (lanes 4q..4q+3) via butterfly shfl
#pragma unroll
  for (int off = 1; off <= 2; off <<= 1) {
    float om = __shfl_xor(m, off, 64);
    float ol = __shfl_xor(lsum, off, 64);
    float nm = fmaxf(m, om);
    float w1 = __expf(m - nm), w2 = __expf(om - nm);
    lsum = lsum * w1 + ol * w2;
#pragma unroll
    for (int i = 0; i < 8; ++i) {
      float oa = __shfl_xor(a[i], off, 64);
      a[i] = a[i] * w1 + oa * w2;
    }
    m = nm;
  }
  float inv = 1.0f / lsum;
  int bq = j >> 7, sq = ((j & 127) << 3) | slo;
  float* op = ao + (((size_t)((bq << 10) | sq)) << 6) + (h << 3) + (ks << 1);
  *(float2*)op = make_float2(a[2 * ks] * inv, a[2 * ks + 1] * inv);
}

// K4: fused  x = LN2( x1 + relu(x1@W1+b1)@W2+b2 ),  x1 = LN1( x + ao@Wo+bo )
__global__ __launch_bounds__(256) void k_fused(
    const float* x_in, const float* __restrict__ ao,
    const float* __restrict__ Wo, const float* __restrict__ bo,
    const float* __restrict__ g1, const float* __restrict__ be1,
    const float* __restrict__ W1, const float* __restrict__ b1,
    const float* __restrict__ W2, const float* __restrict__ b2,
    const float* __restrict__ g2, const float* __restrict__ be2,
    float* x_out) {
  int t = threadIdx.x, r = t >> 6, c = t & 63;
  int row = (blockIdx.x << 2) | r;
  __shared__ float x1s[4][64];
  __shared__ float h1s[4][256];
  float acc = bo[c];
  const float* ap = ao + (size_t)row * 64;
#pragma unroll 4
  for (int k4 = 0; k4 < 16; ++k4) {
    float4 av = *(const float4*)(ap + 4 * k4);
    acc = fmaf(av.x, Wo[(4 * k4 + 0) * 64 + c], acc);
    acc = fmaf(av.y, Wo[(4 * k4 + 1) * 64 + c], acc);
    acc = fmaf(av.z, Wo[(4 * k4 + 2) * 64 + c], acc);
    acc = fmaf(av.w, Wo[(4 * k4 + 3) * 64 + c], acc);
  }
  float y = acc + x_in[(size_t)row * 64 + c];
  float s1 = wave_sum64(y), s2 = wave_sum64(y * y);
  float mean = s1 * 0.015625f, var = s2 * 0.015625f - mean * mean;
  float x1v = (y - mean) * rsqrtf(var + EPS) * g1[c] + be1[c];
  x1s[r][c] = x1v;
  __syncthreads();
  float4 acc4 = *(const float4*)(b1 + 4 * c);
#pragma unroll 4
  for (int k4 = 0; k4 < 16; ++k4) {
    float4 xv = *(const float4*)(&x1s[r][4 * k4]);
    float4 w0 = *(const float4*)(W1 + (size_t)(4 * k4 + 0) * 256 + 4 * c);
    float4 w1 = *(const float4*)(W1 + (size_t)(4 * k4 + 1) * 256 + 4 * c);
    float4 w2 = *(const float4*)(W1 + (size_t)(4 * k4 + 2) * 256 + 4 * c);
    float4 w3 = *(const float4*)(W1 + (size_t)(4 * k4 + 3) * 256 + 4 * c);
    acc4.x = fmaf(xv.x, w0.x, acc4.x); acc4.y = fmaf(xv.x, w0.y, acc4.y);
    acc4.z = fmaf(xv.x, w0.z, acc4.z); acc4.w = fmaf(xv.x, w0.w, acc4.w);
    acc4.x = fmaf(xv.y, w1.x, acc4.x); acc4.y = fmaf(xv.y, w1.y, acc4.y);
    acc4.z = fmaf(xv.y, w1.z, acc4.z); acc4.w = fmaf(xv.y, w1.w, acc4.w);
    acc4.x = fmaf(xv.z, w2.x, acc4.x); acc4.y = fmaf(xv.z, w2.y, acc4.y);
    acc4.z = fmaf(xv.z, w2.z, acc4.z); acc4.w = fmaf(xv.z, w2.w, acc4.w);
    acc4.x = fmaf(xv.w, w3.x, acc4.x); acc4.y = fmaf(xv.w, w3.y, acc4.y);
    acc4.z = fmaf(xv.w, w3.z, acc4.z); acc4.w = fmaf(xv.w, w3.w, acc4.w);
  }
  acc4.x = fmaxf(acc4.x, 0.f); acc4.y = fmaxf(acc4.y, 0.f);
  acc4.z = fmaxf(acc4.z, 0.f); acc4.w = fmaxf(acc4.w, 0.f);
  *(float4*)(&h1s[r][4 * c]) = acc4;
  __syncthreads();
  float acc2 = b2[c];
#pragma unroll 4
  for (int k4 = 0; k4 < 64; ++k4) {
    float4 hv = *(const float4*)(&h1s[r][4 * k4]);
    acc2 = fmaf(hv.x, W2[(size_t)(4 * k4 + 0) * 64 + c], acc2);
    acc2 = fmaf(hv.y, W2[(size_t)(4 * k4 + 1) * 64 + c], acc2);
    acc2 = fmaf(hv.z, W2[(size_t)(4 * k4 + 2) * 64 + c], acc2);
    acc2 = fmaf(hv.w, W2[(size_t)(4 * k4 + 3) * 64 + c], acc2);
  }
  float y2 = acc2 + x1v;
  float t1 = wave_sum64(y2), t2 = wave_sum64(y2 * y2);
  float mean2 = t1 * 0.015625f, var2 = t2 * 0.015625f - mean2 * mean2;
  x_out[(size_t)row * 64 + c] =
      (y2 - mean2) * rsqrtf(var2 + EPS) * g2[c] + be2[c];
}

// K6: out = x @ W_fc + b_fc
__global__ __launch_bounds__(256) void k_head(
    const float* __restrict__ x, const float* __restrict__ Wfc,
    const float* __restrict__ bfc, float* __restrict__ out) {
  int gid = blockIdx.x * 256 + threadIdx.x;
  int r = gid >> 5, o = gid & 31;
  if (o >= 31) return;
  float acc = bfc[o];
  const float* xr = x + (size_t)r * 64;
#pragma unroll
  for (int i = 0; i < 64; ++i) acc = fmaf(xr[i], Wfc[i * 31 + o], acc);
  out[(size_t)r * 31 + o] = acc;
}

extern "C" void kernel_launch(void* const* d_in, const int* in_sizes, int n_in,
                              void* d_out, int out_size, void* d_ws, size_t ws_size,
                              hipStream_t stream) {
  const float* weather = (const float*)d_in[0];
  const float* coords  = (const float*)d_in[1];
  const int*   tidx    = (const int*)d_in[2];
  const float* W_emb   = (const float*)d_in[3];
  const float* b_emb   = (const float*)d_in[4];
  const float* W_qkv   = (const float*)d_in[5];
  const float* b_qkv   = (const float*)d_in[6];
  const float* W_out   = (const float*)d_in[7];
  const float* b_out   = (const float*)d_in[8];
  const float* gran    = (const float*)d_in[9];
  const float* g1      = (const float*)d_in[10];
  const float* be1     = (const float*)d_in[11];
  const float* W1      = (const float*)d_in[12];
  const float* b1      = (const float*)d_in[13];
  const float* W2      = (const float*)d_in[14];
  const float* b2      = (const float*)d_in[15];
  const float* g2      = (const float*)d_in[16];
  const float* be2     = (const float*)d_in[17];
  const float* W_fc    = (const float*)d_in[18];
  const float* b_fc    = (const float*)d_in[19];
  float* out = (float*)d_out;

  // workspace (floats): x(0.5M) | q2(0.5M) | kv2(1M) | ao(0.5M) = 10 MB
  float* x   = (float*)d_ws;
  float* q2  = x + 8192 * 64;
  float* kv2 = q2 + 8192 * 64;
  float* ao  = kv2 + 8192 * 128;

  k_embed<<<8192, 64, 0, stream>>>(weather, coords, W_emb, b_emb, x);
  for (int l = 0; l < 3; ++l) {
    k_qkv<<<1024, 192, 0, stream>>>(x, W_qkv + l * 64 * 192, b_qkv + l * 192,
                                    gran + l * 31 * 64, tidx, q2, kv2);
    k_attn<<<1024, 256, 0, stream>>>(q2, kv2, ao);
    k_fused<<<2048, 256, 0, stream>>>(x, ao, W_out + l * 64 * 64, b_out + l * 64,
                                      g1 + l * 64, be1 + l * 64,
                                      W1 + l * 64 * 256, b1 + l * 256,
                                      W2 + l * 256 * 64, b2 + l * 64,
                                      g2 + l * 64, be2 + l * 64, x);
  }
  k_head<<<1024, 256, 0, stream>>>(x, W_fc, b_fc, out);
}

// Round 6
// 298.470 us; speedup vs baseline: 8.0442x; 8.0442x over previous
//
#include <hip/hip_runtime.h>
#include <math.h>

#define EPS 1e-5f

__device__ __forceinline__ float wave_sum64(float v) {
#pragma unroll
  for (int off = 32; off >= 1; off >>= 1) v += __shfl_xor(v, off, 64);
  return v;
}

// K1: x = weather @ W_emb + b_emb + pos_encoding
__global__ __launch_bounds__(64) void k_embed(
    const float* __restrict__ weather, const float* __restrict__ coords,
    const float* __restrict__ W_emb, const float* __restrict__ b_emb,
    float* __restrict__ x) {
  int row = blockIdx.x;  // b*1024 + s
  int e = threadIdx.x;
  int b = row >> 10, s = row & 1023;
  __shared__ float wrow[32];
  if (e < 31) wrow[e] = weather[row * 31 + e];
  __syncthreads();
  float acc = b_emb[e];
#pragma unroll
  for (int i = 0; i < 31; ++i) acc = fmaf(wrow[i], W_emb[i * 64 + e], acc);
  int g = e >> 2, rem = e & 3;
  float div = __expf(-0.5756462732485115f * (float)g);
  float pe;
  if (rem == 0)      pe = sinf((float)s * div);
  else if (rem == 1) pe = cosf((float)s * div);
  else if (rem == 2) pe = sinf(coords[b * 2 + 0] * 0.017453292519943295f * div);
  else               pe = cosf(coords[b * 2 + 1] * 0.017453292519943295f * div);
  x[row * 64 + e] = acc + pe;
}

// K2: qkv projection, written straight into attention-friendly layouts:
//   q2[bh][s2][8]   (gran added)
//   kv2[bh][key][16] = K(8) || V(8)  (gran added to K)
// bh = 8*(s%8)+h ; s2 = b*128 + s/8 ; hd = e%8.  8 rows/block, thread = col.
__global__ __launch_bounds__(192) void k_qkv(
    const float* __restrict__ x, const float* __restrict__ Wq,
    const float* __restrict__ bq, const float* __restrict__ gran,
    const int* __restrict__ tidx, float* __restrict__ q2,
    float* __restrict__ kv2) {
  int t = threadIdx.x;
  int row0 = blockIdx.x << 3;
  float acc[8];
  float bias = bq[t];
#pragma unroll
  for (int r = 0; r < 8; ++r) acc[r] = bias;
  const float* xp = x + (size_t)row0 * 64;
#pragma unroll 4
  for (int k4 = 0; k4 < 16; ++k4) {
    float4 xv[8];
#pragma unroll
    for (int r = 0; r < 8; ++r) xv[r] = *(const float4*)(xp + r * 64 + k4 * 4);
    float w0 = Wq[(4 * k4 + 0) * 192 + t];
    float w1 = Wq[(4 * k4 + 1) * 192 + t];
    float w2 = Wq[(4 * k4 + 2) * 192 + t];
    float w3 = Wq[(4 * k4 + 3) * 192 + t];
#pragma unroll
    for (int r = 0; r < 8; ++r) {
      acc[r] = fmaf(xv[r].x, w0, acc[r]);
      acc[r] = fmaf(xv[r].y, w1, acc[r]);
      acc[r] = fmaf(xv[r].z, w2, acc[r]);
      acc[r] = fmaf(xv[r].w, w3, acc[r]);
    }
  }
  int cq = t & 63;
  int hh = cq >> 3, hd = t & 7;
  bool isqk = t < 128;
  int b = row0 >> 10, shi = (row0 & 1023) >> 3;
  int s2 = (b << 7) | shi;  // same for all 8 rows (row0 % 8 == 0)
#pragma unroll
  for (int r = 0; r < 8; ++r) {
    float o = acc[r];
    if (isqk) o += gran[tidx[2 * r + 1] * 64 + cq];  // (row0+r)%8 == r
    int bh = (r << 3) | hh;
    size_t base = ((size_t)(bh << 10) | s2);
    if (t < 64)       q2[(base << 3) + hd] = o;
    else if (t < 128) kv2[(base << 4) + hd] = o;
    else              kv2[(base << 4) + 8 + hd] = o;
  }
}

// K3: flash attention. Block = (bh, 64-query chunk), 256 threads =
// 64 queries x 4 key-splits (lane = 4*ql + ks, split-merge via shfl).
// K/V streamed through a 16KB double-buffered LDS tile (128 keys/tile).
//
// Register discipline (rounds 3-5 lesson): the old 4-keys-in-flight batch +
// online-rescale chain invited the scheduler to hoist 16 float4 of LDS data;
// every VGPR cap (64/128/none) either spilled or blew up. This version:
//   - deferred-max softmax: rescale only if batch max exceeds m+8 (cold
//     path; p bounded by e^8, exp(-1e30)=0 folds in the first batch)
//   - one K/V row live at a time; unroll 2 to curb hoisting
// Natural liveness ~70 VGPR; (256,2) cap = 128 leaves slack.
__global__ __launch_bounds__(256, 2) void k_attn(
    const float* __restrict__ q2, const float* __restrict__ kv2,
    float* __restrict__ ao) {
  int bh = blockIdx.x >> 4, chunk = blockIdx.x & 15;
  int slo = bh >> 3, h = bh & 7;
  int t = threadIdx.x;
  int ql = t >> 2, ks = t & 3;
  int j = (chunk << 6) | ql;  // query s2

  const float* qb = q2 + ((((size_t)bh << 10) | j) << 3);
  float4 q0 = *(const float4*)qb;
  float4 q1 = *(const float4*)(qb + 4);
  const float scl = 0.35355339059327373f;  // 8^-0.5 folded into q
  q0.x *= scl; q0.y *= scl; q0.z *= scl; q0.w *= scl;
  q1.x *= scl; q1.y *= scl; q1.z *= scl; q1.w *= scl;

  __shared__ float tile[2][2048];  // [buf][128 keys x 16 floats]
  const float* kvb = kv2 + ((size_t)bh << 14);

  // prologue: stage tile 0
  float4 p0 = *(const float4*)(kvb + (t << 2));
  float4 p1 = *(const float4*)(kvb + ((t + 256) << 2));
  ((float4*)tile[0])[t] = p0;
  ((float4*)tile[0])[t + 256] = p1;

  float m = -1e30f, lsum = 0.f;
  float a[8];
#pragma unroll
  for (int i = 0; i < 8; ++i) a[i] = 0.f;

  for (int tt = 0; tt < 8; ++tt) {
    if (tt < 7) {  // prefetch next tile into regs (in flight across barrier)
      const float* srcn = kvb + ((size_t)(tt + 1) << 11);
      p0 = *(const float4*)(srcn + (t << 2));
      p1 = *(const float4*)(srcn + ((t + 256) << 2));
    }
    __syncthreads();  // tile[tt&1] ready; prev compute done everywhere
    const float4* tb = (const float4*)tile[tt & 1];
#pragma unroll 2
    for (int g = 0; g < 8; ++g) {
      int i0 = (g << 4) | ks;  // keys i0, i0+4, i0+8, i0+12
      const float4* r0 = tb + ((i0 + 0) << 2);
      const float4* r1 = tb + ((i0 + 4) << 2);
      const float4* r2 = tb + ((i0 + 8) << 2);
      const float4* r3 = tb + ((i0 + 12) << 2);
      float s0, s1, s2, s3;
      {
        float4 ka = r0[0], kb = r0[1];
        s0 = fmaf(q0.x, ka.x, fmaf(q0.y, ka.y, fmaf(q0.z, ka.z, fmaf(q0.w, ka.w,
             fmaf(q1.x, kb.x, fmaf(q1.y, kb.y, fmaf(q1.z, kb.z, q1.w * kb.w)))))));
      }
      {
        float4 ka = r1[0], kb = r1[1];
        s1 = fmaf(q0.x, ka.x, fmaf(q0.y, ka.y, fmaf(q0.z, ka.z, fmaf(q0.w, ka.w,
             fmaf(q1.x, kb.x, fmaf(q1.y, kb.y, fmaf(q1.z, kb.z, q1.w * kb.w)))))));
      }
      {
        float4 ka = r2[0], kb = r2[1];
        s2 = fmaf(q0.x, ka.x, fmaf(q0.y, ka.y, fmaf(q0.z, ka.z, fmaf(q0.w, ka.w,
             fmaf(q1.x, kb.x, fmaf(q1.y, kb.y, fmaf(q1.z, kb.z, q1.w * kb.w)))))));
      }
      {
        float4 ka = r3[0], kb = r3[1];
        s3 = fmaf(q0.x, ka.x, fmaf(q0.y, ka.y, fmaf(q0.z, ka.z, fmaf(q0.w, ka.w,
             fmaf(q1.x, kb.x, fmaf(q1.y, kb.y, fmaf(q1.z, kb.z, q1.w * kb.w)))))));
      }
      float mx = fmaxf(fmaxf(s0, s1), fmaxf(s2, s3));
      if (mx > m + 8.f) {  // cold: first batch (exp(-1e30)=0) or outlier growth
        float esc = __expf(m - mx);
        lsum *= esc;
#pragma unroll
        for (int i = 0; i < 8; ++i) a[i] *= esc;
        m = mx;
      }
      float e0 = __expf(s0 - m), e1 = __expf(s1 - m);
      float e2 = __expf(s2 - m), e3 = __expf(s3 - m);
      lsum += (e0 + e1) + (e2 + e3);
      {
        float4 va = r0[2], vb = r0[3];
        a[0] = fmaf(e0, va.x, a[0]); a[1] = fmaf(e0, va.y, a[1]);
        a[2] = fmaf(e0, va.z, a[2]); a[3] = fmaf(e0, va.w, a[3]);
        a[4] = fmaf(e0, vb.x, a[4]); a[5] = fmaf(e0, vb.y, a[5]);
        a[6] = fmaf(e0, vb.z, a[6]); a[7] = fmaf(e0, vb.w, a[7]);
      }
      {
        float4 va = r1[2], vb = r1[3];
        a[0] = fmaf(e1, va.x, a[0]); a[1] = fmaf(e1, va.y, a[1]);
        a[2] = fmaf(e1, va.z, a[2]); a[3] = fmaf(e1, va.w, a[3]);
        a[4] = fmaf(e1, vb.x, a[4]); a[5] = fmaf(e1, vb.y, a[5]);
        a[6] = fmaf(e1, vb.z, a[6]); a[7] = fmaf(e1, vb.w, a[7]);
      }
      {
        float4 va = r2[2], vb = r2[3];
        a[0] = fmaf(e2, va.x, a[0]); a[1] = fmaf(e2, va.y, a[1]);
        a[2] = fmaf(e2, va.z, a[2]); a[3] = fmaf(e2, va.w, a[3]);
        a[4] = fmaf(e2, vb.x, a[4]); a[5] = fmaf(e2, vb.y, a[5]);
        a[6] = fmaf(e2, vb.z, a[6]); a[7] = fmaf(e2, vb.w, a[7]);
      }
      {
        float4 va = r3[2], vb = r3[3];
        a[0] = fmaf(e3, va.x, a[0]); a[1] = fmaf(e3, va.y, a[1]);
        a[2] = fmaf(e3, va.z, a[2]); a[3] = fmaf(e3, va.w, a[3]);
        a[4] = fmaf(e3, vb.x, a[4]); a[5] = fmaf(e3, vb.y, a[5]);
        a[6] = fmaf(e3, vb.z, a[6]); a[7] = fmaf(e3, vb.w, a[7]);
      }
    }
    if (tt < 7) {  // safe: everyone passed this iter's barrier
      ((float4*)tile[(tt + 1) & 1])[t] = p0;
      ((float4*)tile[(tt + 1) & 1])[t + 256] = p1;
    }
  }

  // merge the 4 key-splits (lanes 4q..4q+3) via butterfly shfl
  // (m is a reference point, not necessarily the true max — merge math is
  // identical: partials are sum/acc of exp(s - m).)
#pragma unroll
  for (int off = 1; off <= 2; off <<= 1) {
    float om = __shfl_xor(m, off, 64);
    float ol = __shfl_xor(lsum, off, 64);
    float nm = fmaxf(m, om);
    float w1 = __expf(m - nm), w2 = __expf(om - nm);
    lsum = lsum * w1 + ol * w2;
#pragma unroll
    for (int i = 0; i < 8; ++i) {
      float oa = __shfl_xor(a[i], off, 64);
      a[i] = a[i] * w1 + oa * w2;
    }
    m = nm;
  }
  float inv = 1.0f / lsum;
  int bq = j >> 7, sq = ((j & 127) << 3) | slo;
  float* op = ao + (((size_t)((bq << 10) | sq)) << 6) + (h << 3) + (ks << 1);
  *(float2*)op = make_float2(a[2 * ks] * inv, a[2 * ks + 1] * inv);
}

// K4: fused  x = LN2( x1 + relu(x1@W1+b1)@W2+b2 ),  x1 = LN1( x + ao@Wo+bo )
__global__ __launch_bounds__(256) void k_fused(
    const float* x_in, const float* __restrict__ ao,
    const float* __restrict__ Wo, const float* __restrict__ bo,
    const float* __restrict__ g1, const float* __restrict__ be1,
    const float* __restrict__ W1, const float* __restrict__ b1,
    const float* __restrict__ W2, const float* __restrict__ b2,
    const float* __restrict__ g2, const float* __restrict__ be2,
    float* x_out) {
  int t = threadIdx.x, r = t >> 6, c = t & 63;
  int row = (blockIdx.x << 2) | r;
  __shared__ float x1s[4][64];
  __shared__ float h1s[4][256];
  float acc = bo[c];
  const float* ap = ao + (size_t)row * 64;
#pragma unroll 4
  for (int k4 = 0; k4 < 16; ++k4) {
    float4 av = *(const float4*)(ap + 4 * k4);
    acc = fmaf(av.x, Wo[(4 * k4 + 0) * 64 + c], acc);
    acc = fmaf(av.y, Wo[(4 * k4 + 1) * 64 + c], acc);
    acc = fmaf(av.z, Wo[(4 * k4 + 2) * 64 + c], acc);
    acc = fmaf(av.w, Wo[(4 * k4 + 3) * 64 + c], acc);
  }
  float y = acc + x_in[(size_t)row * 64 + c];
  float s1 = wave_sum64(y), s2 = wave_sum64(y * y);
  float mean = s1 * 0.015625f, var = s2 * 0.015625f - mean * mean;
  float x1v = (y - mean) * rsqrtf(var + EPS) * g1[c] + be1[c];
  x1s[r][c] = x1v;
  __syncthreads();
  float4 acc4 = *(const float4*)(b1 + 4 * c);
#pragma unroll 4
  for (int k4 = 0; k4 < 16; ++k4) {
    float4 xv = *(const float4*)(&x1s[r][4 * k4]);
    float4 w0 = *(const float4*)(W1 + (size_t)(4 * k4 + 0) * 256 + 4 * c);
    float4 w1 = *(const float4*)(W1 + (size_t)(4 * k4 + 1) * 256 + 4 * c);
    float4 w2 = *(const float4*)(W1 + (size_t)(4 * k4 + 2) * 256 + 4 * c);
    float4 w3 = *(const float4*)(W1 + (size_t)(4 * k4 + 3) * 256 + 4 * c);
    acc4.x = fmaf(xv.x, w0.x, acc4.x); acc4.y = fmaf(xv.x, w0.y, acc4.y);
    acc4.z = fmaf(xv.x, w0.z, acc4.z); acc4.w = fmaf(xv.x, w0.w, acc4.w);
    acc4.x = fmaf(xv.y, w1.x, acc4.x); acc4.y = fmaf(xv.y, w1.y, acc4.y);
    acc4.z = fmaf(xv.y, w1.z, acc4.z); acc4.w = fmaf(xv.y, w1.w, acc4.w);
    acc4.x = fmaf(xv.z, w2.x, acc4.x); acc4.y = fmaf(xv.z, w2.y, acc4.y);
    acc4.z = fmaf(xv.z, w2.z, acc4.z); acc4.w = fmaf(xv.z, w2.w, acc4.w);
    acc4.x = fmaf(xv.w, w3.x, acc4.x); acc4.y = fmaf(xv.w, w3.y, acc4.y);
    acc4.z = fmaf(xv.w, w3.z, acc4.z); acc4.w = fmaf(xv.w, w3.w, acc4.w);
  }
  acc4.x = fmaxf(acc4.x, 0.f); acc4.y = fmaxf(acc4.y, 0.f);
  acc4.z = fmaxf(acc4.z, 0.f); acc4.w = fmaxf(acc4.w, 0.f);
  *(float4*)(&h1s[r][4 * c]) = acc4;
  __syncthreads();
  float acc2 = b2[c];
#pragma unroll 4
  for (int k4 = 0; k4 < 64; ++k4) {
    float4 hv = *(const float4*)(&h1s[r][4 * k4]);
    acc2 = fmaf(hv.x, W2[(size_t)(4 * k4 + 0) * 64 + c], acc2);
    acc2 = fmaf(hv.y, W2[(size_t)(4 * k4 + 1) * 64 + c], acc2);
    acc2 = fmaf(hv.z, W2[(size_t)(4 * k4 + 2) * 64 + c], acc2);
    acc2 = fmaf(hv.w, W2[(size_t)(4 * k4 + 3) * 64 + c], acc2);
  }
  float y2 = acc2 + x1v;
  float t1 = wave_sum64(y2), t2 = wave_sum64(y2 * y2);
  float mean2 = t1 * 0.015625f, var2 = t2 * 0.015625f - mean2 * mean2;
  x_out[(size_t)row * 64 + c] =
      (y2 - mean2) * rsqrtf(var2 + EPS) * g2[c] + be2[c];
}

// K6: out = x @ W_fc + b_fc
__global__ __launch_bounds__(256) void k_head(
    const float* __restrict__ x, const float* __restrict__ Wfc,
    const float* __restrict__ bfc, float* __restrict__ out) {
  int gid = blockIdx.x * 256 + threadIdx.x;
  int r = gid >> 5, o = gid & 31;
  if (o >= 31) return;
  float acc = bfc[o];
  const float* xr = x + (size_t)r * 64;
#pragma unroll
  for (int i = 0; i < 64; ++i) acc = fmaf(xr[i], Wfc[i * 31 + o], acc);
  out[(size_t)r * 31 + o] = acc;
}

extern "C" void kernel_launch(void* const* d_in, const int* in_sizes, int n_in,
                              void* d_out, int out_size, void* d_ws, size_t ws_size,
                              hipStream_t stream) {
  const float* weather = (const float*)d_in[0];
  const float* coords  = (const float*)d_in[1];
  const int*   tidx    = (const int*)d_in[2];
  const float* W_emb   = (const float*)d_in[3];
  const float* b_emb   = (const float*)d_in[4];
  const float* W_qkv   = (const float*)d_in[5];
  const float* b_qkv   = (const float*)d_in[6];
  const float* W_out   = (const float*)d_in[7];
  const float* b_out   = (const float*)d_in[8];
  const float* gran    = (const float*)d_in[9];
  const float* g1      = (const float*)d_in[10];
  const float* be1     = (const float*)d_in[11];
  const float* W1      = (const float*)d_in[12];
  const float* b1      = (const float*)d_in[13];
  const float* W2      = (const float*)d_in[14];
  const float* b2      = (const float*)d_in[15];
  const float* g2      = (const float*)d_in[16];
  const float* be2     = (const float*)d_in[17];
  const float* W_fc    = (const float*)d_in[18];
  const float* b_fc    = (const float*)d_in[19];
  float* out = (float*)d_out;

  // workspace (floats): x(0.5M) | q2(0.5M) | kv2(1M) | ao(0.5M) = 10 MB
  float* x   = (float*)d_ws;
  float* q2  = x + 8192 * 64;
  float* kv2 = q2 + 8192 * 64;
  float* ao  = kv2 + 8192 * 128;

  k_embed<<<8192, 64, 0, stream>>>(weather, coords, W_emb, b_emb, x);
  for (int l = 0; l < 3; ++l) {
    k_qkv<<<1024, 192, 0, stream>>>(x, W_qkv + l * 64 * 192, b_qkv + l * 192,
                                    gran + l * 31 * 64, tidx, q2, kv2);
    k_attn<<<1024, 256, 0, stream>>>(q2, kv2, ao);
    k_fused<<<2048, 256, 0, stream>>>(x, ao, W_out + l * 64 * 64, b_out + l * 64,
                                      g1 + l * 64, be1 + l * 64,
                                      W1 + l * 64 * 256, b1 + l * 256,
                                      W2 + l * 256 * 64, b2 + l * 64,
                                      g2 + l * 64, be2 + l * 64, x);
  }
  k_head<<<1024, 256, 0, stream>>>(x, W_fc, b_fc, out);
}